// Round 1
// baseline (2228.026 us; speedup 1.0000x reference)
//
#include <hip/hip_runtime.h>
#include <math.h>

#define N_NODES 50000
#define N_EDGES 800000
#define D 128          // NODE_DIM
#define DE 10          // EDGE_DIM
#define K_TOT 266      // 2*D + DE
#define TE 64          // edges per block
#define TC 64          // output cols per block (of 128); gate+cand both computed
#define ZSTRIDE 65     // LDS row stride (pad to break bank conflicts)
#define CHUNK1_ROWS 138  // 128 (h[dst]) + 10 (edge_feat)

__device__ __forceinline__ float sigmoid_f(float x) {
    return 1.0f / (1.0f + __expf(-x));
}
__device__ __forceinline__ float softplus_f(float x) {
    // stable: max(x,0) + log1p(exp(-|x|))
    return fmaxf(x, 0.0f) + log1pf(__expf(-fabsf(x)));
}

__global__ __launch_bounds__(256) void edge_gemm_scatter(
    const float* __restrict__ h, const int* __restrict__ ei,
    const float* __restrict__ ef,
    const float* __restrict__ gw, const float* __restrict__ gb,
    const float* __restrict__ cw, const float* __restrict__ cb,
    float* __restrict__ agg)
{
    __shared__ float zs[CHUNK1_ROWS * ZSTRIDE];   // 35.9 KB
    __shared__ int s_src[TE];

    const int t  = threadIdx.x;
    const int bx = blockIdx.x;
    const int eb   = bx >> 1;           // edge-tile index (0..12499)
    const int col0 = (bx & 1) * TC;     // 0 or 64
    const int e0   = eb * TE;
    const int tx = t & 15;              // col group  (16 x 4 cols = 64)
    const int ty = t >> 4;              // edge group (16 x 4 edges = 64)

    const int* srcp = ei;               // edge_index[0]
    const int* dstp = ei + N_EDGES;     // edge_index[1]

    if (t < TE) s_src[t] = srcp[e0 + t];

    float accg[4][4], accc[4][4];
    #pragma unroll
    for (int a = 0; a < 4; ++a)
        #pragma unroll
        for (int b = 0; b < 4; ++b) { accg[a][b] = 0.0f; accc[a][b] = 0.0f; }

    const int wcol = col0 + tx * 4;
    const int zoff = ty * 4;

    // ---------- chunk 0: k = 0..127  (h[src]) ----------
    __syncthreads();   // s_src ready
    #pragma unroll
    for (int it = 0; it < 8; ++it) {
        int lin = it * 256 + t;          // 0..2047 float4 slots
        int e   = lin >> 5;              // 32 float4 per edge row
        int d4  = (lin & 31) << 2;
        const float4 v = *(const float4*)&h[s_src[e] * D + d4];
        zs[(d4 + 0) * ZSTRIDE + e] = v.x;
        zs[(d4 + 1) * ZSTRIDE + e] = v.y;
        zs[(d4 + 2) * ZSTRIDE + e] = v.z;
        zs[(d4 + 3) * ZSTRIDE + e] = v.w;
    }
    __syncthreads();

    for (int k = 0; k < 128; ++k) {
        const float* zr = &zs[k * ZSTRIDE + zoff];
        float zv[4] = { zr[0], zr[1], zr[2], zr[3] };
        const float4 wg = *(const float4*)&gw[k * D + wcol];
        const float4 wc = *(const float4*)&cw[k * D + wcol];
        float wgv[4] = { wg.x, wg.y, wg.z, wg.w };
        float wcv[4] = { wc.x, wc.y, wc.z, wc.w };
        #pragma unroll
        for (int a = 0; a < 4; ++a)
            #pragma unroll
            for (int b = 0; b < 4; ++b) {
                accg[a][b] = fmaf(zv[a], wgv[b], accg[a][b]);
                accc[a][b] = fmaf(zv[a], wcv[b], accc[a][b]);
            }
    }
    __syncthreads();

    // ---------- chunk 1: k = 128..265 (h[dst] rows 0..127, edge_feat rows 128..137) ----------
    #pragma unroll
    for (int it = 0; it < 8; ++it) {
        int lin = it * 256 + t;
        int e   = lin >> 5;
        int d4  = (lin & 31) << 2;
        int dd  = dstp[e0 + e];
        const float4 v = *(const float4*)&h[dd * D + d4];
        zs[(d4 + 0) * ZSTRIDE + e] = v.x;
        zs[(d4 + 1) * ZSTRIDE + e] = v.y;
        zs[(d4 + 2) * ZSTRIDE + e] = v.z;
        zs[(d4 + 3) * ZSTRIDE + e] = v.w;
    }
    for (int lin = t; lin < TE * DE; lin += 256) {
        float v = ef[e0 * DE + lin];     // fully coalesced: lin == e*10+f
        int e = lin / DE;
        int f = lin - e * DE;
        zs[(128 + f) * ZSTRIDE + e] = v;
    }
    __syncthreads();

    for (int k = 0; k < CHUNK1_ROWS; ++k) {
        const int kg = 128 + k;
        const float* zr = &zs[k * ZSTRIDE + zoff];
        float zv[4] = { zr[0], zr[1], zr[2], zr[3] };
        const float4 wg = *(const float4*)&gw[kg * D + wcol];
        const float4 wc = *(const float4*)&cw[kg * D + wcol];
        float wgv[4] = { wg.x, wg.y, wg.z, wg.w };
        float wcv[4] = { wc.x, wc.y, wc.z, wc.w };
        #pragma unroll
        for (int a = 0; a < 4; ++a)
            #pragma unroll
            for (int b = 0; b < 4; ++b) {
                accg[a][b] = fmaf(zv[a], wgv[b], accg[a][b]);
                accc[a][b] = fmaf(zv[a], wcv[b], accc[a][b]);
            }
    }

    // ---------- epilogue: m = sigmoid(g+gb)*softplus(c+cb), scatter to agg[src] ----------
    const float4 gb4 = *(const float4*)&gb[wcol];
    const float4 cb4 = *(const float4*)&cb[wcol];
    float gbv[4] = { gb4.x, gb4.y, gb4.z, gb4.w };
    float cbv[4] = { cb4.x, cb4.y, cb4.z, cb4.w };
    #pragma unroll
    for (int a = 0; a < 4; ++a) {
        int e    = zoff + a;
        int node = s_src[e];
        float* rowp = &agg[node * D + wcol];
        #pragma unroll
        for (int b = 0; b < 4; ++b) {
            float m = sigmoid_f(accg[a][b] + gbv[b]) * softplus_f(accc[a][b] + cbv[b]);
            atomicAdd(&rowp[b], m);
        }
    }
}

__global__ __launch_bounds__(256) void col_stats(
    const float* __restrict__ agg, float* __restrict__ stats)
{
    const int t    = threadIdx.x;
    const int col  = t & 127;
    const int half = t >> 7;          // 0/1
    float s = 0.0f, s2 = 0.0f;
    for (int r = blockIdx.x * 2 + half; r < N_NODES; r += gridDim.x * 2) {
        float v = agg[r * D + col];
        s += v; s2 += v * v;
    }
    atomicAdd(&stats[col], s);
    atomicAdd(&stats[128 + col], s2);
}

__global__ void finalize_stats(
    const float* __restrict__ stats, const float* __restrict__ gamma,
    const float* __restrict__ beta, float* __restrict__ scbi)
{
    int c = threadIdx.x;              // 128 threads
    const float inv_n = 1.0f / (float)N_NODES;
    float mean = stats[c] * inv_n;
    float var  = stats[128 + c] * inv_n - mean * mean;
    var = fmaxf(var, 0.0f);
    float rstd = rsqrtf(var + 1e-5f);
    float sc = rstd * gamma[c];
    scbi[c]       = sc;
    scbi[128 + c] = beta[c] - mean * sc;
}

__global__ __launch_bounds__(256) void out_softplus(
    const float* __restrict__ h, const float* __restrict__ agg,
    const float* __restrict__ scbi, float* __restrict__ out)
{
    __shared__ float sc[128], bi[128];
    int t = threadIdx.x;
    if (t < 128) { sc[t] = scbi[t]; bi[t] = scbi[128 + t]; }
    __syncthreads();
    int idx4 = blockIdx.x * 256 + t;              // float4 index
    int base = idx4 * 4;
    if (base < N_NODES * D) {
        float4 hv = *(const float4*)&h[base];
        float4 av = *(const float4*)&agg[base];
        int c = base & 127;
        float4 o;
        o.x = softplus_f(hv.x + av.x * sc[c + 0] + bi[c + 0]);
        o.y = softplus_f(hv.y + av.y * sc[c + 1] + bi[c + 1]);
        o.z = softplus_f(hv.z + av.z * sc[c + 2] + bi[c + 2]);
        o.w = softplus_f(hv.w + av.w * sc[c + 3] + bi[c + 3]);
        *(float4*)&out[base] = o;
    }
}

extern "C" void kernel_launch(void* const* d_in, const int* in_sizes, int n_in,
                              void* d_out, int out_size, void* d_ws, size_t ws_size,
                              hipStream_t stream) {
    const float* h     = (const float*)d_in[0];
    const int*   ei    = (const int*)  d_in[1];
    const float* ef    = (const float*)d_in[2];
    const float* gw    = (const float*)d_in[3];
    const float* gb    = (const float*)d_in[4];
    const float* cw    = (const float*)d_in[5];
    const float* cb    = (const float*)d_in[6];
    const float* gamma = (const float*)d_in[7];
    const float* beta  = (const float*)d_in[8];
    float* out = (float*)d_out;

    float* agg   = (float*)d_ws;                       // N*D floats
    float* stats = agg + (size_t)N_NODES * D;          // 256 floats (sum, sumsq)
    float* scbi  = stats + 256;                        // 256 floats (scale, bias)

    hipMemsetAsync(d_ws, 0, ((size_t)N_NODES * D + 512) * sizeof(float), stream);

    edge_gemm_scatter<<<(N_EDGES / TE) * 2, 256, 0, stream>>>(h, ei, ef, gw, gb, cw, cb, agg);
    col_stats<<<200, 256, 0, stream>>>(agg, stats);
    finalize_stats<<<1, 128, 0, stream>>>(stats, gamma, beta, scbi);
    out_softplus<<<(N_NODES * D / 4 + 255) / 256, 256, 0, stream>>>(h, agg, scbi, out);
}

// Round 2
// 564.145 us; speedup vs baseline: 3.9494x; 3.9494x over previous
//
#include <hip/hip_runtime.h>
#include <math.h>

#define N_NODES 50000
#define N_EDGES 800000
#define D 128          // NODE_DIM
#define DE 10          // EDGE_DIM
#define K_TOT 266      // 2*D + DE
#define KP 288         // padded K = 9 * 32
#define TE 64          // edges per block
#define ZSTRIDE 296    // bf16 per z row in LDS: 288 + 8 pad (16B-aligned rows, 2-way banks = free)
#define WP_ELEMS (9 * 16 * 64 * 8)   // packed weight elements (bf16)

typedef __bf16 bf16x8 __attribute__((ext_vector_type(8)));
typedef __bf16 bf16x2 __attribute__((ext_vector_type(2)));
typedef float  f32x4  __attribute__((ext_vector_type(4)));

__device__ __forceinline__ float sigmoid_f(float x) {
    return 1.0f / (1.0f + __expf(-x));
}
__device__ __forceinline__ float softplus_f(float x) {
    return fmaxf(x, 0.0f) + log1pf(__expf(-fabsf(x)));
}

// Pack gate_w | cand_w (fp32 [266][128] each) into bf16 B-fragment order for
// v_mfma_f32_16x16x32_bf16. n-tile nb: (nb>>1) selects 16-col block, nb&1
// selects gate(0)/cand(1) — so each wave (4 consecutive nb) holds matching
// gate/cand column pairs. Element (kb, nb, lane, j):
//   k = kb*32 + (lane>>4)*8 + j   (zero for k >= 266)
//   col = (nb>>1)*16 + (lane&15)
__global__ __launch_bounds__(256) void pack_weights(
    const float* __restrict__ gw, const float* __restrict__ cw,
    __bf16* __restrict__ wp)
{
    int idx = blockIdx.x * 256 + threadIdx.x;
    if (idx >= WP_ELEMS) return;
    int j    = idx & 7;
    int lane = (idx >> 3) & 63;
    int nb   = (idx >> 9) & 15;
    int kb   = idx >> 13;
    int k    = kb * 32 + ((lane >> 4) << 3) + j;
    int col  = ((nb >> 1) << 4) + (lane & 15);
    const float* w = (nb & 1) ? cw : gw;
    float v = (k < K_TOT) ? w[k * D + col] : 0.0f;
    wp[idx] = (__bf16)v;
}

__global__ __launch_bounds__(256, 4) void edge_mfma_scatter(
    const float* __restrict__ h, const int* __restrict__ ei,
    const float* __restrict__ ef, const __bf16* __restrict__ wp,
    const float* __restrict__ gb, const float* __restrict__ cb,
    float* __restrict__ agg)
{
    __shared__ __bf16 zs[TE * ZSTRIDE];   // 37,888 B
    __shared__ int s_src[TE];
    __shared__ int s_dst[TE];

    const int t  = threadIdx.x;
    const int e0 = blockIdx.x * TE;
    const int* srcp = ei;
    const int* dstp = ei + N_EDGES;

    if (t < TE) { s_src[t] = srcp[e0 + t]; s_dst[t] = dstp[e0 + t]; }
    __syncthreads();

    // ---- stage z tile (bf16) ----
    // k 0..127: h[src]
    #pragma unroll
    for (int it = 0; it < 8; ++it) {
        int lin = it * 256 + t;          // 2048 float4 slots
        int e   = lin >> 5;
        int d4  = (lin & 31) << 2;
        float4 v = *(const float4*)&h[(size_t)s_src[e] * D + d4];
        bf16x2 p0 = { (__bf16)v.x, (__bf16)v.y };
        bf16x2 p1 = { (__bf16)v.z, (__bf16)v.w };
        *(bf16x2*)&zs[e * ZSTRIDE + d4]     = p0;
        *(bf16x2*)&zs[e * ZSTRIDE + d4 + 2] = p1;
    }
    // k 128..255: h[dst]
    #pragma unroll
    for (int it = 0; it < 8; ++it) {
        int lin = it * 256 + t;
        int e   = lin >> 5;
        int d4  = (lin & 31) << 2;
        float4 v = *(const float4*)&h[(size_t)s_dst[e] * D + d4];
        bf16x2 p0 = { (__bf16)v.x, (__bf16)v.y };
        bf16x2 p1 = { (__bf16)v.z, (__bf16)v.w };
        *(bf16x2*)&zs[e * ZSTRIDE + 128 + d4]     = p0;
        *(bf16x2*)&zs[e * ZSTRIDE + 128 + d4 + 2] = p1;
    }
    // k 256..287: edge_feat (10) + zero pad (22)
    #pragma unroll
    for (int it = 0; it < 8; ++it) {
        int lin = it * 256 + t;          // 2048 = 64 edges * 32 k
        int e   = lin >> 5;
        int kk  = lin & 31;
        float v = (kk < DE) ? ef[(size_t)(e0 + e) * DE + kk] : 0.0f;
        zs[e * ZSTRIDE + 256 + kk] = (__bf16)v;
    }
    __syncthreads();

    // ---- MFMA: [64 x 288] @ [288 x 256] ----
    const int w     = t >> 6;     // wave 0..3 -> n-tiles nb = w*4 .. w*4+3
    const int l     = t & 63;
    const int quad  = l >> 4;
    const int col16 = l & 15;

    f32x4 acc[4][4];              // [mt][nt]
    #pragma unroll
    for (int mt = 0; mt < 4; ++mt)
        #pragma unroll
        for (int nt = 0; nt < 4; ++nt)
            acc[mt][nt] = (f32x4)0.0f;

    #pragma unroll
    for (int kb = 0; kb < 9; ++kb) {
        bf16x8 afr[4];
        #pragma unroll
        for (int mt = 0; mt < 4; ++mt)
            afr[mt] = *(const bf16x8*)&zs[(mt * 16 + col16) * ZSTRIDE + kb * 32 + quad * 8];
        bf16x8 bfr[4];
        #pragma unroll
        for (int nt = 0; nt < 4; ++nt) {
            int nb = w * 4 + nt;
            bfr[nt] = *(const bf16x8*)&wp[(size_t)((kb * 16 + nb) * 64 + l) * 8];
        }
        #pragma unroll
        for (int mt = 0; mt < 4; ++mt)
            #pragma unroll
            for (int nt = 0; nt < 4; ++nt)
                acc[mt][nt] = __builtin_amdgcn_mfma_f32_16x16x32_bf16(
                    afr[mt], bfr[nt], acc[mt][nt], 0, 0, 0);
    }

    // ---- epilogue: m = sigmoid(g+gb)*softplus(c+cb), atomic scatter ----
    const int colA = w * 32 + col16;   // gate/cand pair 0
    const int colB = colA + 16;        // pair 1
    const float gbA = gb[colA], cbA = cb[colA];
    const float gbB = gb[colB], cbB = cb[colB];

    #pragma unroll
    for (int mt = 0; mt < 4; ++mt) {
        #pragma unroll
        for (int r = 0; r < 4; ++r) {
            int e    = mt * 16 + quad * 4 + r;
            int node = s_src[e];
            float m0 = sigmoid_f(acc[mt][0][r] + gbA) * softplus_f(acc[mt][1][r] + cbA);
            atomicAdd(&agg[(size_t)node * D + colA], m0);
            float m1 = sigmoid_f(acc[mt][2][r] + gbB) * softplus_f(acc[mt][3][r] + cbB);
            atomicAdd(&agg[(size_t)node * D + colB], m1);
        }
    }
}

__global__ __launch_bounds__(256) void col_stats(
    const float* __restrict__ agg, float* __restrict__ stats)
{
    const int t    = threadIdx.x;
    const int col  = t & 127;
    const int half = t >> 7;
    float s = 0.0f, s2 = 0.0f;
    for (int r = blockIdx.x * 2 + half; r < N_NODES; r += gridDim.x * 2) {
        float v = agg[(size_t)r * D + col];
        s += v; s2 += v * v;
    }
    atomicAdd(&stats[col], s);
    atomicAdd(&stats[128 + col], s2);
}

__global__ void finalize_stats(
    const float* __restrict__ stats, const float* __restrict__ gamma,
    const float* __restrict__ beta, float* __restrict__ scbi)
{
    int c = threadIdx.x;              // 128 threads
    const float inv_n = 1.0f / (float)N_NODES;
    float mean = stats[c] * inv_n;
    float var  = stats[128 + c] * inv_n - mean * mean;
    var = fmaxf(var, 0.0f);
    float rstd = rsqrtf(var + 1e-5f);
    float sc = rstd * gamma[c];
    scbi[c]       = sc;
    scbi[128 + c] = beta[c] - mean * sc;
}

__global__ __launch_bounds__(256) void out_softplus(
    const float* __restrict__ h, const float* __restrict__ agg,
    const float* __restrict__ scbi, float* __restrict__ out)
{
    __shared__ float sc[128], bi[128];
    int t = threadIdx.x;
    if (t < 128) { sc[t] = scbi[t]; bi[t] = scbi[128 + t]; }
    __syncthreads();
    int idx4 = blockIdx.x * 256 + t;
    int base = idx4 * 4;
    if (base < N_NODES * D) {
        float4 hv = *(const float4*)&h[base];
        float4 av = *(const float4*)&agg[base];
        int c = base & 127;
        float4 o;
        o.x = softplus_f(hv.x + av.x * sc[c + 0] + bi[c + 0]);
        o.y = softplus_f(hv.y + av.y * sc[c + 1] + bi[c + 1]);
        o.z = softplus_f(hv.z + av.z * sc[c + 2] + bi[c + 2]);
        o.w = softplus_f(hv.w + av.w * sc[c + 3] + bi[c + 3]);
        *(float4*)&out[base] = o;
    }
}

extern "C" void kernel_launch(void* const* d_in, const int* in_sizes, int n_in,
                              void* d_out, int out_size, void* d_ws, size_t ws_size,
                              hipStream_t stream) {
    const float* h     = (const float*)d_in[0];
    const int*   ei    = (const int*)  d_in[1];
    const float* ef    = (const float*)d_in[2];
    const float* gw    = (const float*)d_in[3];
    const float* gb    = (const float*)d_in[4];
    const float* cw    = (const float*)d_in[5];
    const float* cb    = (const float*)d_in[6];
    const float* gamma = (const float*)d_in[7];
    const float* beta  = (const float*)d_in[8];
    float* out = (float*)d_out;

    float*  agg   = (float*)d_ws;                         // N*D floats
    float*  stats = agg + (size_t)N_NODES * D;            // 256 floats
    float*  scbi  = stats + 256;                          // 256 floats
    __bf16* wp    = (__bf16*)(scbi + 256);                // WP_ELEMS bf16 (147 KB)

    hipMemsetAsync(d_ws, 0, ((size_t)N_NODES * D + 512) * sizeof(float), stream);
    pack_weights<<<(WP_ELEMS + 255) / 256, 256, 0, stream>>>(gw, cw, wp);
    edge_mfma_scatter<<<N_EDGES / TE, 256, 0, stream>>>(h, ei, ef, wp, gb, cb, agg);
    col_stats<<<200, 256, 0, stream>>>(agg, stats);
    finalize_stats<<<1, 128, 0, stream>>>(stats, gamma, beta, scbi);
    out_softplus<<<(N_NODES * D / 4 + 255) / 256, 256, 0, stream>>>(h, agg, scbi, out);
}

// Round 3
// 514.279 us; speedup vs baseline: 4.3323x; 1.0970x over previous
//
#include <hip/hip_runtime.h>
#include <math.h>

#define N_NODES 50000
#define N_EDGES 800000
#define D 128          // NODE_DIM
#define DE 10          // EDGE_DIM
#define K_TOT 266      // 2*D + DE
#define KP 288         // padded K = 9 * 32
#define TE 64          // edges per block
#define ZSTRIDE 296    // bf16 per z row in LDS: 288 + 8 pad (16B-aligned rows, 2-way banks = free)
#define WP_ELEMS (9 * 16 * 64 * 8)   // packed weight elements (bf16) = 73728

typedef __bf16 bf16x8 __attribute__((ext_vector_type(8)));
typedef __bf16 bf16x4 __attribute__((ext_vector_type(4)));
typedef float  f32x4  __attribute__((ext_vector_type(4)));

// Fast device transcendentals: single HW instruction each (v_exp_f32 = 2^x,
// v_log_f32 = log2, v_rcp_f32). libm log1pf/div are 30+/10+ inst sequences —
// they were the R2 VALU bottleneck (VALUBusy 96%).
__device__ __forceinline__ float fast_sigmoid(float x) {
    float t = __builtin_amdgcn_exp2f(-1.44269504089f * x);
    return __builtin_amdgcn_rcpf(1.0f + t);
}
__device__ __forceinline__ float fast_softplus(float x) {
    float t = __builtin_amdgcn_exp2f(-1.44269504089f * fabsf(x));
    return fmaxf(x, 0.0f) + 0.69314718056f * __builtin_amdgcn_logf(1.0f + t);
}

// ---- pre-pass: convert h and edge_feat to bf16 once (mem-bound, ~15 us) ----
__global__ __launch_bounds__(256) void cvt_h_bf16(
    const float* __restrict__ h, __bf16* __restrict__ hb)
{
    int i4 = blockIdx.x * 256 + threadIdx.x;      // float4 index, 1.6M exactly
    float4 v = *(const float4*)&h[(size_t)i4 * 4];
    bf16x4 o = { (__bf16)v.x, (__bf16)v.y, (__bf16)v.z, (__bf16)v.w };
    *(bf16x4*)&hb[(size_t)i4 * 4] = o;
}

__global__ __launch_bounds__(256) void cvt_ef_bf16(
    const float* __restrict__ ef, __bf16* __restrict__ efb)
{
    int i4 = blockIdx.x * 256 + threadIdx.x;      // 2M float4 exactly
    if (i4 >= N_EDGES * DE / 4) return;
    float4 v = *(const float4*)&ef[(size_t)i4 * 4];
    bf16x4 o = { (__bf16)v.x, (__bf16)v.y, (__bf16)v.z, (__bf16)v.w };
    *(bf16x4*)&efb[(size_t)i4 * 4] = o;
}

// Pack gate_w | cand_w into bf16 B-fragment order for v_mfma_f32_16x16x32_bf16.
// nb>>1 selects 16-col block, nb&1 selects gate(0)/cand(1).
__global__ __launch_bounds__(256) void pack_weights(
    const float* __restrict__ gw, const float* __restrict__ cw,
    __bf16* __restrict__ wp)
{
    int idx = blockIdx.x * 256 + threadIdx.x;
    if (idx >= WP_ELEMS) return;
    int j    = idx & 7;
    int lane = (idx >> 3) & 63;
    int nb   = (idx >> 9) & 15;
    int kb   = idx >> 13;
    int k    = kb * 32 + ((lane >> 4) << 3) + j;
    int col  = ((nb >> 1) << 4) + (lane & 15);
    const float* w = (nb & 1) ? cw : gw;
    float v = (k < K_TOT) ? w[k * D + col] : 0.0f;
    wp[idx] = (__bf16)v;
}

__global__ __launch_bounds__(256, 4) void edge_mfma_scatter(
    const __bf16* __restrict__ hb, const int* __restrict__ ei,
    const __bf16* __restrict__ efb, const __bf16* __restrict__ wp,
    const float* __restrict__ gb, const float* __restrict__ cb,
    float* __restrict__ agg)
{
    __shared__ __bf16 zs[TE * ZSTRIDE];   // 37,888 B
    __shared__ int s_src[TE];
    __shared__ int s_dst[TE];

    const int t  = threadIdx.x;
    const int e0 = blockIdx.x * TE;

    if (t < TE) { s_src[t] = ei[e0 + t]; s_dst[t] = ei[N_EDGES + e0 + t]; }
    __syncthreads();

    // ---- stage z tile: pure bf16x8 16B loads, no cvt ----
    // 64 rows x 128 bf16 from h[src] (region 0) and h[dst] (region 1):
    // 2048 bf16x8 slots = 8 per thread.
    #pragma unroll
    for (int it = 0; it < 8; ++it) {
        int lin = it * 256 + t;
        int region = lin >> 10;            // 0 = src, 1 = dst
        int r   = (lin >> 4) & 63;         // edge row
        int seg = lin & 15;                // 16B segment (8 bf16)
        int node = region ? s_dst[r] : s_src[r];
        bf16x8 v = *(const bf16x8*)&hb[(size_t)node * D + seg * 8];
        *(bf16x8*)&zs[r * ZSTRIDE + region * 128 + seg * 8] = v;
    }
    // k 256..287: edge_feat (10) + zero pad (22): 2048 scalar bf16 slots
    #pragma unroll
    for (int it = 0; it < 8; ++it) {
        int lin = it * 256 + t;
        int e   = lin >> 5;
        int kk  = lin & 31;
        __bf16 v = (kk < DE) ? efb[(size_t)(e0 + e) * DE + kk] : (__bf16)0.0f;
        zs[e * ZSTRIDE + 256 + kk] = v;
    }
    __syncthreads();

    // ---- MFMA: [64 x 288] @ [288 x 256] ----
    const int w     = t >> 6;     // wave 0..3 -> n-tiles nb = w*4 .. w*4+3
    const int l     = t & 63;
    const int quad  = l >> 4;
    const int col16 = l & 15;

    f32x4 acc[4][4];              // [mt][nt]
    #pragma unroll
    for (int mt = 0; mt < 4; ++mt)
        #pragma unroll
        for (int nt = 0; nt < 4; ++nt)
            acc[mt][nt] = (f32x4)0.0f;

    const __bf16* zp  = &zs[col16 * ZSTRIDE + quad * 8];
    const __bf16* wpp = &wp[(size_t)((w * 4) * 64 + l) * 8];

    #pragma unroll
    for (int kb = 0; kb < 9; ++kb) {
        bf16x8 afr[4];
        #pragma unroll
        for (int mt = 0; mt < 4; ++mt)
            afr[mt] = *(const bf16x8*)&zp[mt * 16 * ZSTRIDE + kb * 32];
        bf16x8 bfr[4];
        #pragma unroll
        for (int nt = 0; nt < 4; ++nt)
            bfr[nt] = *(const bf16x8*)&wpp[(size_t)(kb * 16 + nt) * 512];
        #pragma unroll
        for (int mt = 0; mt < 4; ++mt)
            #pragma unroll
            for (int nt = 0; nt < 4; ++nt)
                acc[mt][nt] = __builtin_amdgcn_mfma_f32_16x16x32_bf16(
                    afr[mt], bfr[nt], acc[mt][nt], 0, 0, 0);
    }

    // ---- epilogue: m = sigmoid(g+gb)*softplus(c+cb), atomic scatter ----
    const int colA = w * 32 + col16;   // gate/cand pair 0
    const int colB = colA + 16;        // pair 1
    const float gbA = gb[colA], cbA = cb[colA];
    const float gbB = gb[colB], cbB = cb[colB];

    #pragma unroll
    for (int mt = 0; mt < 4; ++mt) {
        #pragma unroll
        for (int r = 0; r < 4; ++r) {
            int e    = mt * 16 + quad * 4 + r;
            size_t base = (size_t)s_src[e] * D;
            float m0 = fast_sigmoid(acc[mt][0][r] + gbA) * fast_softplus(acc[mt][1][r] + cbA);
            atomicAdd(&agg[base + colA], m0);
            float m1 = fast_sigmoid(acc[mt][2][r] + gbB) * fast_softplus(acc[mt][3][r] + cbB);
            atomicAdd(&agg[base + colB], m1);
        }
    }
}

__global__ __launch_bounds__(256) void col_stats(
    const float* __restrict__ agg, float* __restrict__ stats)
{
    const int t    = threadIdx.x;
    const int col  = t & 127;
    const int half = t >> 7;
    float s = 0.0f, s2 = 0.0f;
    for (int r = blockIdx.x * 2 + half; r < N_NODES; r += gridDim.x * 2) {
        float v = agg[(size_t)r * D + col];
        s += v; s2 += v * v;
    }
    atomicAdd(&stats[col], s);
    atomicAdd(&stats[128 + col], s2);
}

__global__ void finalize_stats(
    const float* __restrict__ stats, const float* __restrict__ gamma,
    const float* __restrict__ beta, float* __restrict__ scbi)
{
    int c = threadIdx.x;              // 128 threads
    const float inv_n = 1.0f / (float)N_NODES;
    float mean = stats[c] * inv_n;
    float var  = stats[128 + c] * inv_n - mean * mean;
    var = fmaxf(var, 0.0f);
    float rstd = rsqrtf(var + 1e-5f);
    float sc = rstd * gamma[c];
    scbi[c]       = sc;
    scbi[128 + c] = beta[c] - mean * sc;
}

__global__ __launch_bounds__(256) void out_softplus(
    const float* __restrict__ h, const float* __restrict__ agg,
    const float* __restrict__ scbi, float* __restrict__ out)
{
    __shared__ float sc[128], bi[128];
    int t = threadIdx.x;
    if (t < 128) { sc[t] = scbi[t]; bi[t] = scbi[128 + t]; }
    __syncthreads();
    int idx4 = blockIdx.x * 256 + t;
    int base = idx4 * 4;
    if (base < N_NODES * D) {
        float4 hv = *(const float4*)&h[base];
        float4 av = *(const float4*)&agg[base];
        int c = base & 127;
        float4 o;
        o.x = fast_softplus(hv.x + av.x * sc[c + 0] + bi[c + 0]);
        o.y = fast_softplus(hv.y + av.y * sc[c + 1] + bi[c + 1]);
        o.z = fast_softplus(hv.z + av.z * sc[c + 2] + bi[c + 2]);
        o.w = fast_softplus(hv.w + av.w * sc[c + 3] + bi[c + 3]);
        *(float4*)&out[base] = o;
    }
}

extern "C" void kernel_launch(void* const* d_in, const int* in_sizes, int n_in,
                              void* d_out, int out_size, void* d_ws, size_t ws_size,
                              hipStream_t stream) {
    const float* h     = (const float*)d_in[0];
    const int*   ei    = (const int*)  d_in[1];
    const float* ef    = (const float*)d_in[2];
    const float* gw    = (const float*)d_in[3];
    const float* gb    = (const float*)d_in[4];
    const float* cw    = (const float*)d_in[5];
    const float* cb    = (const float*)d_in[6];
    const float* gamma = (const float*)d_in[7];
    const float* beta  = (const float*)d_in[8];
    float* out = (float*)d_out;

    float*  agg   = (float*)d_ws;                         // N*D floats (25.6 MB)
    float*  stats = agg + (size_t)N_NODES * D;            // 256 floats
    float*  scbi  = stats + 256;                          // 256 floats
    __bf16* wp    = (__bf16*)(scbi + 256);                // 73728 bf16 (144 KB)
    __bf16* hb    = wp + WP_ELEMS;                        // 6.4M bf16 (12.8 MB)
    __bf16* efb   = hb + (size_t)N_NODES * D;             // 8M bf16 (16 MB)

    hipMemsetAsync(d_ws, 0, ((size_t)N_NODES * D + 512) * sizeof(float), stream);
    cvt_h_bf16<<<N_NODES * D / 4 / 256, 256, 0, stream>>>(h, hb);
    cvt_ef_bf16<<<(N_EDGES * DE / 4 + 255) / 256, 256, 0, stream>>>(ef, efb);
    pack_weights<<<(WP_ELEMS + 255) / 256, 256, 0, stream>>>(gw, cw, wp);
    edge_mfma_scatter<<<N_EDGES / TE, 256, 0, stream>>>(hb, ei, efb, wp, gb, cb, agg);
    col_stats<<<200, 256, 0, stream>>>(agg, stats);
    finalize_stats<<<1, 128, 0, stream>>>(stats, gamma, beta, scbi);
    out_softplus<<<(N_NODES * D / 4 + 255) / 256, 256, 0, stream>>>(h, agg, scbi, out);
}